// Round 1
// 1438.083 us; speedup vs baseline: 1.3987x; 1.3987x over previous
//
#include <hip/hip_runtime.h>
#include <math.h>

#define Bn   4
#define Sn   1024
#define Hn   1024
#define NHn  16
#define DHn  64
#define CLIPV 2.5f
#define QMAX  127.0f

__device__ __forceinline__ void atomicMaxPosF(float* addr, float v) {
    // valid for non-negative floats: same order as unsigned ints
    atomicMax((unsigned int*)addr, __float_as_uint(v));
}

// ---------------- absmax of clip(x, +-CLIP) ----------------
__global__ __launch_bounds__(256) void absmax_kernel(const float* __restrict__ x, int n,
                                                     float* __restrict__ out) {
    float m = 0.0f;
    for (int i = blockIdx.x * blockDim.x + threadIdx.x; i < n; i += gridDim.x * blockDim.x) {
        m = fmaxf(m, fminf(fabsf(x[i]), CLIPV));
    }
#pragma unroll
    for (int off = 32; off > 0; off >>= 1) m = fmaxf(m, __shfl_down(m, off, 64));
    __shared__ float sm[4];
    int lane = threadIdx.x & 63, wid = threadIdx.x >> 6;
    if (lane == 0) sm[wid] = m;
    __syncthreads();
    if (threadIdx.x == 0) {
        float mm = fmaxf(fmaxf(sm[0], sm[1]), fmaxf(sm[2], sm[3]));
        atomicMaxPosF(out, mm);
    }
}

// ---------------- QKV projection GEMM ----------------
// out[m][n] = sum_k dq(x[m][k]) * dq(W[n][k]) + bias[n],  M=4096, N=1024, K=1024
// z selects (Wq,bq,Qf) / (Wk,bk,Kf) / (Wv,bv,Vf). Epilogue: absmax(clip(out)) -> scl[4+z]
__global__ __launch_bounds__(256) void qkv_gemm_kernel(
    const float* __restrict__ x,
    const float* __restrict__ Wq_, const float* __restrict__ Wk_, const float* __restrict__ Wv_,
    const float* __restrict__ bq_, const float* __restrict__ bk_, const float* __restrict__ bv_,
    float* __restrict__ scl,
    float* __restrict__ Qf, float* __restrict__ Kf, float* __restrict__ Vf)
{
    int z = blockIdx.z;
    const float* W    = (z == 0) ? Wq_ : (z == 1) ? Wk_ : Wv_;
    const float* bias = (z == 0) ? bq_ : (z == 1) ? bk_ : bv_;
    float* out        = (z == 0) ? Qf  : (z == 1) ? Kf  : Vf;

    float ax = fmaxf(scl[0], 1e-8f);
    float aw = fmaxf(scl[1 + z], 1e-8f);
    float sx = QMAX / ax, isx = 1.0f / sx;
    float sw = QMAX / aw, isw = 1.0f / sw;

    __shared__ float As[64][68];  // [k][m]  (68: conflict-mitigating pad, keeps 16B alignment)
    __shared__ float Bs[64][68];  // [k][n]

    int m0 = blockIdx.y * 64;
    int n0 = blockIdx.x * 64;
    int tid = threadIdx.x;
    int tx = tid & 15, ty = tid >> 4;

    float acc[4][4] = {};

    for (int k0 = 0; k0 < Hn; k0 += 64) {
        for (int i = 0; i < 16; ++i) {
            int idx = tid + i * 256;
            int r = idx >> 6, c = idx & 63;
            float v = x[(size_t)(m0 + r) * Hn + k0 + c];
            v = fminf(fmaxf(v, -CLIPV), CLIPV);
            As[c][r] = rintf(v * sx) * isx;
            float w = W[(size_t)(n0 + r) * Hn + k0 + c];
            w = fminf(fmaxf(w, -CLIPV), CLIPV);
            Bs[c][r] = rintf(w * sw) * isw;
        }
        __syncthreads();
#pragma unroll
        for (int k = 0; k < 64; ++k) {
            float4 a  = *(const float4*)&As[k][ty * 4];
            float4 bv = *(const float4*)&Bs[k][tx * 4];
            const float* ap = (const float*)&a;
            const float* bp = (const float*)&bv;
#pragma unroll
            for (int i = 0; i < 4; ++i)
#pragma unroll
                for (int j = 0; j < 4; ++j) acc[i][j] += ap[i] * bp[j];
        }
        __syncthreads();
    }

    float lmax = 0.0f;
#pragma unroll
    for (int i = 0; i < 4; ++i) {
        int m = m0 + ty * 4 + i;
        float4 o;
        float* op = (float*)&o;
#pragma unroll
        for (int j = 0; j < 4; ++j) {
            int n = n0 + tx * 4 + j;
            float v = acc[i][j] + bias[n];
            op[j] = v;
            lmax = fmaxf(lmax, fminf(fabsf(v), CLIPV));
        }
        *(float4*)&out[(size_t)m * Hn + n0 + tx * 4] = o;
    }
#pragma unroll
    for (int off = 32; off > 0; off >>= 1) lmax = fmaxf(lmax, __shfl_down(lmax, off, 64));
    __shared__ float sm2[4];
    int lane = tid & 63, wid = tid >> 6;
    if (lane == 0) sm2[wid] = lmax;
    __syncthreads();
    if (tid == 0)
        atomicMaxPosF(&scl[4 + z], fmaxf(fmaxf(sm2[0], sm2[1]), fmaxf(sm2[2], sm2[3])));
}

// ---------------- requantize Q,K in place; emit v_q in [B,NH,S,DH] ----------------
__global__ __launch_bounds__(256) void requant_kernel(
    float* __restrict__ Qf, float* __restrict__ Kf, const float* __restrict__ Vf,
    const float* __restrict__ scl, float* __restrict__ vq)
{
    int e4 = blockIdx.x * blockDim.x + threadIdx.x;  // float4 index, 0..1048575
    size_t e = (size_t)e4 * 4;
    float aq = fmaxf(scl[4], 1e-8f), ak = fmaxf(scl[5], 1e-8f), av = fmaxf(scl[6], 1e-8f);
    float sq = QMAX / aq, isq = 1.0f / sq;
    float sk = QMAX / ak, isk = 1.0f / sk;
    float sv = QMAX / av, isv = 1.0f / sv;

#define DQ4(vec, s, is)                                                       \
    {                                                                         \
        float* p = (float*)&vec;                                              \
        _Pragma("unroll") for (int t = 0; t < 4; ++t) {                        \
            float c = fminf(fmaxf(p[t], -CLIPV), CLIPV);                      \
            p[t] = rintf(c * (s)) * (is);                                     \
        }                                                                     \
    }

    float4 q = ((const float4*)Qf)[e4];
    DQ4(q, sq, isq);
    ((float4*)Qf)[e4] = q;

    float4 k = ((const float4*)Kf)[e4];
    DQ4(k, sk, isk);
    ((float4*)Kf)[e4] = k;

    float4 v = ((const float4*)Vf)[e4];
    DQ4(v, sv, isv);
    int d = (int)(e & 63);
    int h = (int)((e >> 6) & 15);
    int s = (int)((e >> 10) & 1023);
    int b = (int)(e >> 20);
    size_t vo = (((size_t)(b * NHn + h) * Sn) + s) * DHn + d;
    ((float4*)vq)[vo >> 2] = v;
#undef DQ4
}

// ---------------- scores = Qd.Kd^T / 8 + mask ----------------
__global__ __launch_bounds__(256) void scores_kernel(
    const float* __restrict__ Qd, const float* __restrict__ Kd,
    const float* __restrict__ mask, float* __restrict__ scores)
{
    int bh = blockIdx.z, b = bh >> 4, h = bh & 15;
    int q0 = blockIdx.y * 64, c0 = blockIdx.x * 64;
    __shared__ float Qs[64][68];  // [d][row]
    __shared__ float Ks[64][68];  // [d][col]
    int tid = threadIdx.x, tx = tid & 15, ty = tid >> 4;
    for (int i = 0; i < 16; ++i) {
        int idx = tid + i * 256;
        int r = idx >> 6, d = idx & 63;
        Qs[d][r] = Qd[((size_t)b * Sn + q0 + r) * Hn + h * DHn + d];
        Ks[d][r] = Kd[((size_t)b * Sn + c0 + r) * Hn + h * DHn + d];
    }
    __syncthreads();
    float acc[4][4] = {};
#pragma unroll
    for (int d = 0; d < 64; ++d) {
        float4 a  = *(const float4*)&Qs[d][ty * 4];
        float4 bv = *(const float4*)&Ks[d][tx * 4];
        const float* ap = (const float*)&a;
        const float* bp = (const float*)&bv;
#pragma unroll
        for (int i = 0; i < 4; ++i)
#pragma unroll
            for (int j = 0; j < 4; ++j) acc[i][j] += ap[i] * bp[j];
    }
#pragma unroll
    for (int i = 0; i < 4; ++i) {
        int qi = q0 + ty * 4 + i;
        float4 o;
        float* op = (float*)&o;
#pragma unroll
        for (int j = 0; j < 4; ++j)
            op[j] = acc[i][j] * 0.125f + mask[b * Sn + c0 + tx * 4 + j];
        *(float4*)&scores[((size_t)bh * Sn + qi) * Sn + c0 + tx * 4] = o;
    }
}

// ---------------- row softmax; track global max prob ----------------
// One WAVE per row (no barriers, no LDS). Each lane holds 16 elements
// (4x float4 in flight -> 4 KB outstanding per wave), reductions via
// __shfl_xor (all lanes get the result, no broadcast round-trip).
// Grid-stride over rows; ONE pmax atomic per wave at the end.
__global__ __launch_bounds__(256) void softmax_kernel(
    const float* __restrict__ scores, float* __restrict__ probs, float* __restrict__ pmax)
{
    const int lane = threadIdx.x & 63;
    const int widx = threadIdx.x >> 6;
    const int nwaves = gridDim.x * 4;
    const int nrows = Bn * NHn * Sn;
    float pm = 0.0f;
    for (int row = blockIdx.x * 4 + widx; row < nrows; row += nwaves) {
        const float4* src = (const float4*)(scores + (size_t)row * Sn);
        float4 v0 = src[lane];
        float4 v1 = src[lane + 64];
        float4 v2 = src[lane + 128];
        float4 v3 = src[lane + 192];
        float m = fmaxf(fmaxf(fmaxf(v0.x, v0.y), fmaxf(v0.z, v0.w)),
                        fmaxf(fmaxf(v1.x, v1.y), fmaxf(v1.z, v1.w)));
        m = fmaxf(m, fmaxf(fmaxf(fmaxf(v2.x, v2.y), fmaxf(v2.z, v2.w)),
                           fmaxf(fmaxf(v3.x, v3.y), fmaxf(v3.z, v3.w))));
#pragma unroll
        for (int off = 1; off < 64; off <<= 1) m = fmaxf(m, __shfl_xor(m, off, 64));
        float4 e0, e1, e2, e3;
        e0.x = expf(v0.x - m); e0.y = expf(v0.y - m); e0.z = expf(v0.z - m); e0.w = expf(v0.w - m);
        e1.x = expf(v1.x - m); e1.y = expf(v1.y - m); e1.z = expf(v1.z - m); e1.w = expf(v1.w - m);
        e2.x = expf(v2.x - m); e2.y = expf(v2.y - m); e2.z = expf(v2.z - m); e2.w = expf(v2.w - m);
        e3.x = expf(v3.x - m); e3.y = expf(v3.y - m); e3.z = expf(v3.z - m); e3.w = expf(v3.w - m);
        float s = ((e0.x + e0.y) + (e0.z + e0.w)) + ((e1.x + e1.y) + (e1.z + e1.w)) +
                  ((e2.x + e2.y) + (e2.z + e2.w)) + ((e3.x + e3.y) + (e3.z + e3.w));
#pragma unroll
        for (int off = 1; off < 64; off <<= 1) s += __shfl_xor(s, off, 64);
        float inv = 1.0f / s;
        float4* dst = (float4*)(probs + (size_t)row * Sn);
        float4 p;
        p.x = e0.x * inv; p.y = e0.y * inv; p.z = e0.z * inv; p.w = e0.w * inv;
        dst[lane] = p;
        p.x = e1.x * inv; p.y = e1.y * inv; p.z = e1.z * inv; p.w = e1.w * inv;
        dst[lane + 64] = p;
        p.x = e2.x * inv; p.y = e2.y * inv; p.z = e2.z * inv; p.w = e2.w * inv;
        dst[lane + 128] = p;
        p.x = e3.x * inv; p.y = e3.y * inv; p.z = e3.z * inv; p.w = e3.w * inv;
        dst[lane + 192] = p;
        // max prob of this row is exp(0)*inv = inv
        pm = fmaxf(pm, inv);
    }
#pragma unroll
    for (int off = 1; off < 64; off <<= 1) pm = fmaxf(pm, __shfl_xor(pm, off, 64));
    if (lane == 0) atomicMaxPosF(pmax, pm);
}

// ---------------- context_ = dq(probs) . v_q ; context = transpose ----------------
__global__ __launch_bounds__(256) void pv_kernel(
    const float* __restrict__ probs, const float* __restrict__ vq,
    const float* __restrict__ scl, float* __restrict__ ctx_, float* __restrict__ ctx)
{
    int bh = blockIdx.z, b = bh >> 4, h = bh & 15;
    int s0 = blockIdx.x * 64;
    float ap = fmaxf(scl[7], 1e-8f);
    float sp = QMAX / ap, isp = 1.0f / sp;
    __shared__ float Ps[64][68];  // [k][row]
    __shared__ float Vs[64][68];  // [k][d]
    int tid = threadIdx.x, tx = tid & 15, ty = tid >> 4;
    float acc[4][4] = {};
    for (int k0 = 0; k0 < Sn; k0 += 64) {
        for (int i = 0; i < 16; ++i) {
            int idx = tid + i * 256;
            int r = idx >> 6, c = idx & 63;
            float p = probs[((size_t)bh * Sn + s0 + r) * Sn + k0 + c];
            Ps[c][r] = rintf(p * sp) * isp;  // clip at 2.5 is a no-op for probs
            Vs[r][c] = vq[((size_t)bh * Sn + k0 + r) * DHn + c];
        }
        __syncthreads();
#pragma unroll
        for (int k = 0; k < 64; ++k) {
            float4 a  = *(const float4*)&Ps[k][ty * 4];
            float4 bv = *(const float4*)&Vs[k][tx * 4];
            const float* app = (const float*)&a;
            const float* bp  = (const float*)&bv;
#pragma unroll
            for (int i = 0; i < 4; ++i)
#pragma unroll
                for (int j = 0; j < 4; ++j) acc[i][j] += app[i] * bp[j];
        }
        __syncthreads();
    }
#pragma unroll
    for (int i = 0; i < 4; ++i) {
        int s = s0 + ty * 4 + i;
        float4 o = {acc[i][0], acc[i][1], acc[i][2], acc[i][3]};
        *(float4*)&ctx_[((size_t)bh * Sn + s) * DHn + tx * 4] = o;
        *(float4*)&ctx[((size_t)b * Sn + s) * Hn + h * DHn + tx * 4] = o;
    }
}

extern "C" void kernel_launch(void* const* d_in, const int* in_sizes, int n_in,
                              void* d_out, int out_size, void* d_ws, size_t ws_size,
                              hipStream_t stream) {
    const float* hidden = (const float*)d_in[0];
    const float* mask   = (const float*)d_in[1];
    const float* Wq     = (const float*)d_in[2];
    const float* bq     = (const float*)d_in[3];
    const float* Wk     = (const float*)d_in[4];
    const float* bk     = (const float*)d_in[5];
    const float* Wv     = (const float*)d_in[6];
    const float* bv     = (const float*)d_in[7];

    float* out    = (float*)d_out;
    float* ctx    = out;                       // [B,S,H]        4,194,304
    float* scores = ctx + (size_t)Bn * Sn * Hn;        // [B,NH,S,S] 67,108,864
    float* probs  = scores + (size_t)Bn * NHn * Sn * Sn;
    float* ctx_   = probs + (size_t)Bn * NHn * Sn * Sn; // [B,NH,S,DH]
    float* vq     = ctx_ + (size_t)Bn * Sn * Hn;        // [B,NH,S,DH]

    float* scl = (float*)d_ws;                 // 8 scales (256 B reserved)
    float* Qf  = scl + 64;                     // [B,S,H] fp32
    float* Kf  = Qf + (size_t)Bn * Sn * Hn;
    float* Vf  = Kf + (size_t)Bn * Sn * Hn;

    hipMemsetAsync(d_ws, 0, 256, stream);

    absmax_kernel<<<1024, 256, 0, stream>>>(hidden, Bn * Sn * Hn, &scl[0]);
    absmax_kernel<<<512, 256, 0, stream>>>(Wq, Hn * Hn, &scl[1]);
    absmax_kernel<<<512, 256, 0, stream>>>(Wk, Hn * Hn, &scl[2]);
    absmax_kernel<<<512, 256, 0, stream>>>(Wv, Hn * Hn, &scl[3]);

    qkv_gemm_kernel<<<dim3(16, 64, 3), 256, 0, stream>>>(
        hidden, Wq, Wk, Wv, bq, bk, bv, scl, Qf, Kf, Vf);

    requant_kernel<<<4096, 256, 0, stream>>>(Qf, Kf, Vf, scl, vq);

    scores_kernel<<<dim3(16, 16, 64), 256, 0, stream>>>(Qf, Kf, mask, scores);

    softmax_kernel<<<4096, 256, 0, stream>>>(scores, probs, &scl[7]);

    pv_kernel<<<dim3(16, 1, 64), 256, 0, stream>>>(probs, vq, scl, ctx_, ctx);
}